// Round 10
// baseline (486.880 us; speedup 1.0000x reference)
//
#include <hip/hip_runtime.h>
#include <math.h>

#define DI __device__ __forceinline__

constexpr int BB = 64;     // batch
constexpr int TT = 128;    // action steps (obs/rewards have TT+1)
constexpr int SS = 512;    // states
constexpr int AA = 16;     // actions
constexpr int OO = 4096;   // observations
constexpr float LOG2PI = 1.8378770664093453f;
constexpr float LOG4096 = 8.317766166719343f;  // log(16*256)

typedef float f32x4 __attribute__((ext_vector_type(4)));

// LDS-only barrier: drains LDS ops then barriers (does NOT drain vmcnt,
// so in-flight global fragment loads survive across it).
DI void lds_barrier() {
    asm volatile("s_waitcnt lgkmcnt(0)\n\ts_barrier" ::: "memory");
}

// ---------------- fp8 e4m3fn converter (RTNE), x in [0, 448) ----------------
DI unsigned int f32_to_e4m3(float x) {
    unsigned int u = __float_as_uint(x);
    unsigned int lsb = (u >> 20) & 1u;
    unsigned int rounded = u + 0x7ffffu + lsb;          // RTNE into 3-bit mantissa
    int e8 = (int)(rounded >> 23) - 120;                // 127 - 7
    unsigned int m3 = (rounded >> 20) & 7u;
    unsigned int norm = ((unsigned int)e8 << 3) | m3;
    int sub = __float2int_rn(x * 512.0f);               // subnormal: multiples of 2^-9
    return (e8 <= 0) ? (unsigned int)sub : norm;
}

// ---------------- reduction helpers (wave64) ----------------
DI float bflyMax(float v) {
#pragma unroll
    for (int off = 32; off; off >>= 1) v = fmaxf(v, __shfl_xor(v, off));
    return v;
}
DI float bflySum(float v) {
#pragma unroll
    for (int off = 32; off; off >>= 1) v += __shfl_xor(v, off);
    return v;
}
DI float halfMax(float v) {
#pragma unroll
    for (int off = 16; off; off >>= 1) v = fmaxf(v, __shfl_xor(v, off));
    return v;
}
DI float halfSum(float v) {
#pragma unroll
    for (int off = 16; off; off >>= 1) v += __shfl_xor(v, off);
    return v;
}

// ---------------- ONE fused precompute launch ----------------
// blocks 0..255  : pack — softmax + fp8 quantize (x256) + MFMA-B-fragment
//                  swizzle of the transition matrices (R3 layout).
// blocks 256..287: obs log-softmax + transpose. Each block OWNS 16 s-rows:
//                  one wave per row computes mls = max + log(sumexp) (no
//                  cross-block stats, no mo/lo globals), then re-reads the
//                  L2-hot rows and writes obsT[o][s0..s0+16) as 4x float4 =
//                  exactly one 64-B line per (thread,o). This removes the
//                  stats->transpose kernel boundary: precompute is a single
//                  launch and the total launch count drops to 2.
__global__ __launch_bounds__(1024) void k_pre(const float* __restrict__ tl,
                                              unsigned char* __restrict__ PB,
                                              const float* __restrict__ ol,
                                              float* __restrict__ obsT) {
    __shared__ unsigned char lds[16384];
    __shared__ float mls[16];
    const int bid = blockIdx.x;
    const int tid = threadIdx.x;

    if (bid < 256) {
        // ---- pack: PB byte addr = (a*16+kt)*16384 + ntp*1024 + lane*16 + (nt&1)*8 + j
        const int a = bid >> 4;
        const int kt = bid & 15;
        const int r = tid >> 5;       // 0..31
        const int nt = tid & 31;      // 0..31
        const int k = kt * 32 + r;
        const float* row = tl + ((size_t)a * SS + k) * SS + nt * 16;

        float x[16];
#pragma unroll
        for (int i = 0; i < 4; ++i) {
            float4 v = ((const float4*)row)[i];
            x[4 * i] = v.x; x[4 * i + 1] = v.y; x[4 * i + 2] = v.z; x[4 * i + 3] = v.w;
        }
        float mx = -INFINITY;
#pragma unroll
        for (int i = 0; i < 16; ++i) mx = fmaxf(mx, x[i]);
        mx = halfMax(mx);   // row lives in one 32-lane half
        float e[16];
        float sm = 0.f;
#pragma unroll
        for (int i = 0; i < 16; ++i) { e[i] = __expf(x[i] - mx); sm += e[i]; }
        sm = halfSum(sm);
        const float scale = 256.0f / sm;

        const int base = (nt >> 1) * 1024 + ((r >> 3) * 16) * 16 + (nt & 1) * 8 + (r & 7);
#pragma unroll
        for (int i = 0; i < 16; ++i) {
            lds[base + i * 16] = (unsigned char)f32_to_e4m3(e[i] * scale);
        }
        __syncthreads();

        ulonglong2* dst = (ulonglong2*)(PB + (size_t)(a * 16 + kt) * 16384);
        dst[tid] = ((const ulonglong2*)lds)[tid];
    } else {
        // ---- obs log-softmax + transpose: 16 rows/block, 1 wave per row ----
        const int s0 = (bid - 256) * 16;
        const int rw = tid >> 6;      // 0..15 = row within group = wave index
        const int lane = tid & 63;
        const float* in = ol + (size_t)(s0 + rw) * OO;

        // phase 1: per-row stats (wave-local bfly reductions)
        float mx = -INFINITY;
#pragma unroll 4
        for (int k = 0; k < 64; ++k) mx = fmaxf(mx, in[lane + k * 64]);
        mx = bflyMax(mx);
        float sm = 0.f;
#pragma unroll 4
        for (int k = 0; k < 64; ++k) sm += __expf(in[lane + k * 64] - mx);
        sm = bflySum(sm);
        if (lane == 0) mls[rw] = mx + __logf(sm);
        __syncthreads();

        // phase 2: transposed write, one 64-B line per (thread, o)
        float ml[16];
#pragma unroll
        for (int j = 0; j < 16; ++j) ml[j] = mls[j];
#pragma unroll
        for (int oo = 0; oo < 4; ++oo) {
            const int o = tid + oo * 1024;
            float w[16];
#pragma unroll
            for (int j = 0; j < 16; ++j)
                w[j] = ol[(size_t)(s0 + j) * OO + o] - ml[j];
            float4* dst = (float4*)(obsT + (size_t)o * SS + s0);
            dst[0] = make_float4(w[0], w[1], w[2], w[3]);
            dst[1] = make_float4(w[4], w[5], w[6], w[7]);
            dst[2] = make_float4(w[8], w[9], w[10], w[11]);
            dst[3] = make_float4(w[12], w[13], w[14], w[15]);
        }
    }
}

// ---------------- main sequential-scan kernel (R2/R9 structure, verbatim) ---
// one block per batch element, 512 threads = 8 waves, thread == state.
// Cross-step double-buffered register pipeline (sets F/G, loop unrolled x2):
// during step t's phase B, chunks 8..15 issue step t+1's chunk 0..7 loads
// into the other set. Register-only lqprev handoff via shuffles. 2 LDS-only
// barriers per step (in-flight global loads survive). Best measured k_main
// (377 us); 8 structural variants (R0-R8) bracket it at 377-626, so this
// sits at the per-CU panel-ingest wall (~36 B/cy sustained).
__global__ __launch_bounds__(512, 2) void k_main(
    const float* __restrict__ regime, const int* __restrict__ obs,
    const float* __restrict__ rewards, const float* __restrict__ dones,
    const int* __restrict__ actions, const float* __restrict__ prior_logits,
    const unsigned char* __restrict__ PB, const float* __restrict__ obsT,
    const float* __restrict__ policy_logits, const float* __restrict__ r_mu,
    const float* __restrict__ r_logsig, float* __restrict__ out) {
    __shared__ float wrm[8], wrs[8];
    __shared__ unsigned char p8[4 * 144 + 16];  // [quad][16 kt x 8B], 144-pad
    __shared__ int obs_l[TT + 1];
    __shared__ float rew_l[TT + 1];
    __shared__ float done_l[TT + 1];
    __shared__ int act_l[TT];

    const int b = blockIdx.x;
    const int tid = threadIdx.x;
    const int wv = tid >> 6, lane = tid & 63, quad = lane >> 4;
    const int s = tid;
    const int wvl16 = wv * 2048 + lane * 16;
    const int p8idx = ((s >> 3) & 3) * 144 + (s >> 5) * 8 + (s & 7);

    // ---- one-time preloads ----
    if (tid <= TT) {
        obs_l[tid] = obs[tid * BB + b];
        rew_l[tid] = rewards[tid * BB + b];
        done_l[tid] = dones[tid * BB + b];
        if (tid < TT) act_l[tid] = actions[tid * BB + b];
    }
    // transposed log-softmax policy -> 16 registers per thread
    float la16[16];
    {
        const float4* pr4 = (const float4*)(policy_logits + (size_t)s * AA);
        float4 v0 = pr4[0], v1 = pr4[1], v2 = pr4[2], v3 = pr4[3];
        la16[0] = v0.x; la16[1] = v0.y; la16[2] = v0.z; la16[3] = v0.w;
        la16[4] = v1.x; la16[5] = v1.y; la16[6] = v1.z; la16[7] = v1.w;
        la16[8] = v2.x; la16[9] = v2.y; la16[10] = v2.z; la16[11] = v2.w;
        la16[12] = v3.x; la16[13] = v3.y; la16[14] = v3.z; la16[15] = v3.w;
        float mx = la16[0];
#pragma unroll
        for (int i = 1; i < 16; ++i) mx = fmaxf(mx, la16[i]);
        float sm = 0.f;
#pragma unroll
        for (int i = 0; i < 16; ++i) sm += __expf(la16[i] - mx);
        float ls = mx + __logf(sm);
#pragma unroll
        for (int i = 0; i < 16; ++i) la16[i] -= ls;
    }
    const float rm = r_mu[s];
    const float rls = r_logsig[s];
    const float inv_sig = __expf(-rls);
    const float reg = regime[b];

    // inline prior log-softmax (its barriers also publish the preloads)
    float px = prior_logits[s];
    {
        float wm0 = bflyMax(px);
        if (lane == 0) wrm[wv] = wm0;
    }
    lds_barrier();
    float pm = wrm[0];
#pragma unroll
    for (int i = 1; i < 8; ++i) pm = fmaxf(pm, wrm[i]);
    {
        float ws0 = bflySum(__expf(px - pm));
        if (lane == 0) wrs[wv] = ws0;
    }
    lds_barrier();
    float psum = wrs[0];
#pragma unroll
    for (int i = 1; i < 8; ++i) psum += wrs[i];
    float base_reg = px - pm - __logf(psum);   // prior_reg; loop-carried in reg

    // ---- prologue: issue step-0 chunks 0..7 into set F + obsv for t=0 ----
    ulonglong2 fA[8], fB[8], gA[8], gB[8];
    {
        const int a0 = __builtin_amdgcn_readfirstlane(act_l[0]);
        const unsigned char* P0 = PB + (size_t)a0 * (16 * 16384) + wvl16;
#pragma unroll
        for (int c = 0; c < 8; ++c) {
            fA[c] = *(const ulonglong2*)(P0 + c * 16384);
            fB[c] = *(const ulonglong2*)(P0 + c * 16384 + 1024);
        }
    }
    float obsv = obsT[(size_t)obs_l[0] * SS + s];

    float log_prob = 0.f;
    float was_done = 0.f;

// chunks 0..7: MFMA from CA/CB[c], refill CA/CB[c] with this step's chunk c+8
#define CHUNK_L(c, CA, CB)                                                      \
    {                                                                           \
        long af = *(const long long*)(p8 + quad * 144 + (c) * 8);               \
        acc0 = __builtin_amdgcn_mfma_f32_16x16x32_fp8_fp8((long)CA[(c)].x, af, acc0, 0, 0, 0); \
        acc1 = __builtin_amdgcn_mfma_f32_16x16x32_fp8_fp8((long)CA[(c)].y, af, acc1, 0, 0, 0); \
        acc2 = __builtin_amdgcn_mfma_f32_16x16x32_fp8_fp8((long)CB[(c)].x, af, acc2, 0, 0, 0); \
        acc3 = __builtin_amdgcn_mfma_f32_16x16x32_fp8_fp8((long)CB[(c)].y, af, acc3, 0, 0, 0); \
        CA[(c)] = *(const ulonglong2*)(Pw_ + ((c) + 8) * 16384);                \
        CB[(c)] = *(const ulonglong2*)(Pw_ + ((c) + 8) * 16384 + 1024);         \
    }
// chunks 8..15: MFMA from CA/CB[c-8], issue NEXT step's chunk c-8 into NA/NB
#define CHUNK_H(c, CA, CB, NA, NB)                                              \
    {                                                                           \
        long af = *(const long long*)(p8 + quad * 144 + (c) * 8);               \
        acc0 = __builtin_amdgcn_mfma_f32_16x16x32_fp8_fp8((long)CA[(c) - 8].x, af, acc0, 0, 0, 0); \
        acc1 = __builtin_amdgcn_mfma_f32_16x16x32_fp8_fp8((long)CA[(c) - 8].y, af, acc1, 0, 0, 0); \
        acc2 = __builtin_amdgcn_mfma_f32_16x16x32_fp8_fp8((long)CB[(c) - 8].x, af, acc2, 0, 0, 0); \
        acc3 = __builtin_amdgcn_mfma_f32_16x16x32_fp8_fp8((long)CB[(c) - 8].y, af, acc3, 0, 0, 0); \
        NA[(c) - 8] = *(const ulonglong2*)(Pn_ + ((c) - 8) * 16384);            \
        NB[(c) - 8] = *(const ulonglong2*)(Pn_ + ((c) - 8) * 16384 + 1024);     \
    }

#define STEP(T, CA, CB, NA, NB)                                                 \
    {                                                                           \
        const int t_ = (T);                                                     \
        const float r_ = rew_l[t_];                                             \
        const int a_ = __builtin_amdgcn_readfirstlane(act_l[t_]);               \
        const float d_ = done_l[t_];                                            \
        const float done_ = fmaxf(was_done, d_);                                \
        const unsigned char* Pw_ = PB + (size_t)a_ * (16 * 16384) + wvl16;      \
        const int tn_ = (t_ + 1 < TT) ? t_ + 1 : 0;                             \
        const int an_ = __builtin_amdgcn_readfirstlane(act_l[tn_]);             \
        const unsigned char* Pn_ = PB + (size_t)an_ * (16 * 16384) + wvl16;     \
        float obsv_next_ = obsT[(size_t)obs_l[t_ + 1] * SS + s];                \
        /* ---- phase A: emission + action term + block softmax ---- */        \
        float diff_ = (r_ - rm) * inv_sig;                                      \
        float emis_ = obsv - 0.5f * diff_ * diff_ - rls - 0.5f * LOG2PI;        \
        float la_ = la16[0];                                                    \
        _Pragma("unroll")                                                       \
        for (int i = 1; i < 16; ++i) la_ = (a_ == i) ? la16[i] : la_;           \
        if (done_ == 1.0f || reg == 1.0f) la_ = 0.f;                            \
        float lq_ = base_reg + emis_ + la_;                                     \
        float wmax_ = bflyMax(lq_);                                             \
        if (lane == 0) wrm[wv] = wmax_;                                         \
        lds_barrier(); /* B1 */                                                 \
        float m_ = wrm[0];                                                      \
        _Pragma("unroll")                                                       \
        for (int i = 1; i < 8; ++i) m_ = fmaxf(m_, wrm[i]);                     \
        float exv_ = __expf(lq_ - m_);                                          \
        p8[p8idx] = (unsigned char)f32_to_e4m3(exv_ * 16.0f);                   \
        float wsum_ = bflySum(exv_);                                            \
        if (lane == 0) wrs[wv] = wsum_;                                         \
        lds_barrier(); /* B2 (publishes p8) */                                  \
        float sum_ = wrs[0];                                                    \
        _Pragma("unroll")                                                       \
        for (int i = 1; i < 8; ++i) sum_ += wrs[i];                             \
        float lse_ = m_ + __logf(sum_);                                         \
        float lqo_ = lse_ * (1.0f - was_done);                                  \
        if (!isinf(log_prob)) log_prob += lqo_;                                 \
        was_done = done_;                                                       \
        /* ---- phase B: 16 ktiles; roll this step's 8..15 + next step's 0..7 */\
        const float basev_ = m_ - lqo_ - LOG4096;                               \
        f32x4 acc0 = {0.f, 0.f, 0.f, 0.f};                                      \
        f32x4 acc1 = {0.f, 0.f, 0.f, 0.f};                                      \
        f32x4 acc2 = {0.f, 0.f, 0.f, 0.f};                                      \
        f32x4 acc3 = {0.f, 0.f, 0.f, 0.f};                                      \
        CHUNK_L(0, CA, CB)  CHUNK_L(1, CA, CB)  CHUNK_L(2, CA, CB)              \
        CHUNK_L(3, CA, CB)  CHUNK_L(4, CA, CB)  CHUNK_L(5, CA, CB)              \
        CHUNK_L(6, CA, CB)  CHUNK_L(7, CA, CB)                                  \
        CHUNK_H(8, CA, CB, NA, NB)   CHUNK_H(9, CA, CB, NA, NB)                 \
        CHUNK_H(10, CA, CB, NA, NB)  CHUNK_H(11, CA, CB, NA, NB)                \
        CHUNK_H(12, CA, CB, NA, NB)  CHUNK_H(13, CA, CB, NA, NB)                \
        CHUNK_H(14, CA, CB, NA, NB)  CHUNK_H(15, CA, CB, NA, NB)                \
        /* ---- register-only handoff: state wv*64+16q+l = acc_q[0]@lane l */   \
        float t0_ = __shfl(acc0[0], lane & 15);                                 \
        float t1_ = __shfl(acc1[0], lane & 15);                                 \
        float t2_ = __shfl(acc2[0], lane & 15);                                 \
        float t3_ = __shfl(acc3[0], lane & 15);                                 \
        float av_ = quad == 0 ? t0_ : (quad == 1 ? t1_ : (quad == 2 ? t2_ : t3_)); \
        base_reg = basev_ + __logf(av_);                                        \
        obsv = obsv_next_;                                                      \
        asm volatile("" ::: "memory"); /* pin NXT loads inside this step */     \
    }

    for (int t = 0; t < TT; t += 2) {
        STEP(t, fA, fB, gA, gB)
        STEP(t + 1, gA, gB, fA, fB)
    }
#undef STEP
#undef CHUNK_L
#undef CHUNK_H

    // final step t = TT (no action term, no transition)
    {
        const float r = rew_l[TT];
        float diff = (r - rm) * inv_sig;
        float emis = obsv - 0.5f * diff * diff - rls - 0.5f * LOG2PI;
        float lq = base_reg + emis;
        float wmax = bflyMax(lq);
        if (lane == 0) wrm[wv] = wmax;
        lds_barrier();
        float m = wrm[0];
#pragma unroll
        for (int i = 1; i < 8; ++i) m = fmaxf(m, wrm[i]);
        float wsum = bflySum(__expf(lq - m));
        if (lane == 0) wrs[wv] = wsum;
        lds_barrier();
        float sum = wrs[0];
#pragma unroll
        for (int i = 1; i < 8; ++i) sum += wrs[i];
        float lse = m + __logf(sum);
        float lq_ord = lse * (1.0f - was_done);
        if (!isinf(log_prob)) log_prob += lq_ord;
    }

    if (tid == 0) out[b] = log_prob;
}

// ---------------- launch ----------------
extern "C" void kernel_launch(void* const* d_in, const int* in_sizes, int n_in,
                              void* d_out, int out_size, void* d_ws, size_t ws_size,
                              hipStream_t stream) {
    const float* regime = (const float*)d_in[0];
    const int* obs = (const int*)d_in[1];
    const float* rewards = (const float*)d_in[2];
    const float* dones = (const float*)d_in[3];
    const int* actions = (const int*)d_in[4];
    const float* prior_logits = (const float*)d_in[5];
    const float* trans_logits = (const float*)d_in[6];
    const float* obs_logits = (const float*)d_in[7];
    const float* policy_logits = (const float*)d_in[8];
    const float* r_mu = (const float*)d_in[9];
    const float* r_logsig = (const float*)d_in[10];
    float* out = (float*)d_out;

    char* ws = (char*)d_ws;
    unsigned char* PB = (unsigned char*)ws;                    // A*S*S fp8 = 4 MB
    float* obsT = (float*)(ws + (size_t)AA * SS * SS);         // O*S fp32 = 8 MB

    k_pre<<<288, 1024, 0, stream>>>(trans_logits, PB, obs_logits, obsT);
    k_main<<<BB, 512, 0, stream>>>(regime, obs, rewards, dones, actions, prior_logits,
                                   PB, obsT, policy_logits, r_mu, r_logsig, out);
}

// Round 11
// 465.983 us; speedup vs baseline: 1.0448x; 1.0448x over previous
//
#include <hip/hip_runtime.h>
#include <math.h>

#define DI __device__ __forceinline__

constexpr int BB = 64;     // batch
constexpr int TT = 128;    // action steps (obs/rewards have TT+1)
constexpr int SS = 512;    // states
constexpr int AA = 16;     // actions
constexpr int OO = 4096;   // observations
constexpr float LOG2PI = 1.8378770664093453f;
constexpr float LOG4096 = 8.317766166719343f;  // log(16*256)

typedef float f32x4 __attribute__((ext_vector_type(4)));

// LDS-only barrier: drains LDS ops then barriers (does NOT drain vmcnt,
// so in-flight global fragment loads survive across it).
DI void lds_barrier() {
    asm volatile("s_waitcnt lgkmcnt(0)\n\ts_barrier" ::: "memory");
}

// ---------------- fp8 e4m3fn converter (RTNE), x in [0, 448) ----------------
DI unsigned int f32_to_e4m3(float x) {
    unsigned int u = __float_as_uint(x);
    unsigned int lsb = (u >> 20) & 1u;
    unsigned int rounded = u + 0x7ffffu + lsb;          // RTNE into 3-bit mantissa
    int e8 = (int)(rounded >> 23) - 120;                // 127 - 7
    unsigned int m3 = (rounded >> 20) & 7u;
    unsigned int norm = ((unsigned int)e8 << 3) | m3;
    int sub = __float2int_rn(x * 512.0f);               // subnormal: multiples of 2^-9
    return (e8 <= 0) ? (unsigned int)sub : norm;
}

// ---------------- reduction helpers (wave64) ----------------
DI float bflyMax(float v) {
#pragma unroll
    for (int off = 32; off; off >>= 1) v = fmaxf(v, __shfl_xor(v, off));
    return v;
}
DI float bflySum(float v) {
#pragma unroll
    for (int off = 32; off; off >>= 1) v += __shfl_xor(v, off);
    return v;
}
DI float halfMax(float v) {
#pragma unroll
    for (int off = 16; off; off >>= 1) v = fmaxf(v, __shfl_xor(v, off));
    return v;
}
DI float halfSum(float v) {
#pragma unroll
    for (int off = 16; off; off >>= 1) v += __shfl_xor(v, off);
    return v;
}

// ---------------- precompute: fused pack + obs_stats ----------------
// blocks 0..255  : k_pack body (softmax + fp8 quantize + fragment swizzle)
// blocks 256..383: obs row stats, 4 rows/block x 256 threads/row
__global__ __launch_bounds__(1024) void k_pre(const float* __restrict__ tl,
                                              unsigned char* __restrict__ PB,
                                              const float* __restrict__ ol,
                                              float* __restrict__ mo,
                                              float* __restrict__ lo) {
    __shared__ unsigned char lds[16384];
    __shared__ float wr2[16], ws2[16];
    const int bid = blockIdx.x;
    const int tid = threadIdx.x;

    if (bid < 256) {
        // ---- pack: PB byte addr = (a*16+kt)*16384 + ntp*1024 + lane*16 + (nt&1)*8 + j
        const int a = bid >> 4;
        const int kt = bid & 15;
        const int r = tid >> 5;       // 0..31
        const int nt = tid & 31;      // 0..31
        const int k = kt * 32 + r;
        const float* row = tl + ((size_t)a * SS + k) * SS + nt * 16;

        float x[16];
#pragma unroll
        for (int i = 0; i < 4; ++i) {
            float4 v = ((const float4*)row)[i];
            x[4 * i] = v.x; x[4 * i + 1] = v.y; x[4 * i + 2] = v.z; x[4 * i + 3] = v.w;
        }
        float mx = -INFINITY;
#pragma unroll
        for (int i = 0; i < 16; ++i) mx = fmaxf(mx, x[i]);
        mx = halfMax(mx);   // row lives in one 32-lane half
        float e[16];
        float sm = 0.f;
#pragma unroll
        for (int i = 0; i < 16; ++i) { e[i] = __expf(x[i] - mx); sm += e[i]; }
        sm = halfSum(sm);
        const float scale = 256.0f / sm;

        const int base = (nt >> 1) * 1024 + ((r >> 3) * 16) * 16 + (nt & 1) * 8 + (r & 7);
#pragma unroll
        for (int i = 0; i < 16; ++i) {
            lds[base + i * 16] = (unsigned char)f32_to_e4m3(e[i] * scale);
        }
        __syncthreads();

        ulonglong2* dst = (ulonglong2*)(PB + (size_t)(a * 16 + kt) * 16384);
        dst[tid] = ((const ulonglong2*)lds)[tid];
    } else {
        // ---- obs stats: row group r = tid>>8 (4 rows), u = tid&255 ----
        const int r = tid >> 8;
        const int u = tid & 255;
        const int wir = (tid >> 6) & 3;           // wave index within row group
        const int srow = (bid - 256) * 4 + r;
        const float* in = ol + (size_t)srow * OO;

        float mx = -INFINITY;
#pragma unroll
        for (int k = 0; k < 16; ++k) mx = fmaxf(mx, in[u + k * 256]);
        mx = bflyMax(mx);
        if ((tid & 63) == 0) wr2[r * 4 + wir] = mx;
        __syncthreads();
        float m = fmaxf(fmaxf(wr2[r * 4], wr2[r * 4 + 1]),
                        fmaxf(wr2[r * 4 + 2], wr2[r * 4 + 3]));
        float sm = 0.f;
#pragma unroll
        for (int k = 0; k < 16; ++k) sm += __expf(in[u + k * 256] - m);
        sm = bflySum(sm);
        if ((tid & 63) == 0) ws2[r * 4 + wir] = sm;
        __syncthreads();
        if (u == 0) {
            float sum = ws2[r * 4] + ws2[r * 4 + 1] + ws2[r * 4 + 2] + ws2[r * 4 + 3];
            mo[srow] = m;
            lo[srow] = __logf(sum);
        }
    }
}

__global__ __launch_bounds__(256) void k_obsT(const float* __restrict__ ol,
                                              const float* __restrict__ mo,
                                              const float* __restrict__ lo,
                                              float* __restrict__ obsT) {
    __shared__ float tile[64][65];
    const int tO = blockIdx.x % (OO / 64);
    const int tS = blockIdx.x / (OO / 64);
    const int o0 = tO * 64, s0 = tS * 64;
    const int cc = threadIdx.x & 63, rr = threadIdx.x >> 6;
#pragma unroll
    for (int j = 0; j < 16; ++j) {
        int r = rr + j * 4;
        tile[r][cc] = ol[(size_t)(s0 + r) * OO + o0 + cc] - mo[s0 + r] - lo[s0 + r];
    }
    __syncthreads();
#pragma unroll
    for (int j = 0; j < 16; ++j) {
        int r = rr + j * 4;
        obsT[(size_t)(o0 + r) * SS + s0 + cc] = tile[cc][r];
    }
}

// ---------------- main sequential-scan kernel (R2 structure, verbatim) ------
// one block per batch element, 512 threads = 8 waves, thread == state.
// Cross-step double-buffered register pipeline (sets F/G, loop unrolled x2):
// during step t's phase B, chunks 8..15 issue step t+1's chunk 0..7 loads
// into the other set. Register-only lqprev handoff via shuffles. 2 LDS-only
// barriers per step (in-flight global loads survive). Best measured k_main
// (375-377 us); 8 structural variants (R0-R8) bracket it at 377-626, so this
// sits at the per-CU panel-ingest wall (~36 B/cy sustained).
__global__ __launch_bounds__(512, 2) void k_main(
    const float* __restrict__ regime, const int* __restrict__ obs,
    const float* __restrict__ rewards, const float* __restrict__ dones,
    const int* __restrict__ actions, const float* __restrict__ prior_logits,
    const unsigned char* __restrict__ PB, const float* __restrict__ obsT,
    const float* __restrict__ policy_logits, const float* __restrict__ r_mu,
    const float* __restrict__ r_logsig, float* __restrict__ out) {
    __shared__ float wrm[8], wrs[8];
    __shared__ unsigned char p8[4 * 144 + 16];  // [quad][16 kt x 8B], 144-pad
    __shared__ int obs_l[TT + 1];
    __shared__ float rew_l[TT + 1];
    __shared__ float done_l[TT + 1];
    __shared__ int act_l[TT];

    const int b = blockIdx.x;
    const int tid = threadIdx.x;
    const int wv = tid >> 6, lane = tid & 63, quad = lane >> 4;
    const int s = tid;
    const int wvl16 = wv * 2048 + lane * 16;
    const int p8idx = ((s >> 3) & 3) * 144 + (s >> 5) * 8 + (s & 7);

    // ---- one-time preloads ----
    if (tid <= TT) {
        obs_l[tid] = obs[tid * BB + b];
        rew_l[tid] = rewards[tid * BB + b];
        done_l[tid] = dones[tid * BB + b];
        if (tid < TT) act_l[tid] = actions[tid * BB + b];
    }
    // transposed log-softmax policy -> 16 registers per thread
    float la16[16];
    {
        const float4* pr4 = (const float4*)(policy_logits + (size_t)s * AA);
        float4 v0 = pr4[0], v1 = pr4[1], v2 = pr4[2], v3 = pr4[3];
        la16[0] = v0.x; la16[1] = v0.y; la16[2] = v0.z; la16[3] = v0.w;
        la16[4] = v1.x; la16[5] = v1.y; la16[6] = v1.z; la16[7] = v1.w;
        la16[8] = v2.x; la16[9] = v2.y; la16[10] = v2.z; la16[11] = v2.w;
        la16[12] = v3.x; la16[13] = v3.y; la16[14] = v3.z; la16[15] = v3.w;
        float mx = la16[0];
#pragma unroll
        for (int i = 1; i < 16; ++i) mx = fmaxf(mx, la16[i]);
        float sm = 0.f;
#pragma unroll
        for (int i = 0; i < 16; ++i) sm += __expf(la16[i] - mx);
        float ls = mx + __logf(sm);
#pragma unroll
        for (int i = 0; i < 16; ++i) la16[i] -= ls;
    }
    const float rm = r_mu[s];
    const float rls = r_logsig[s];
    const float inv_sig = __expf(-rls);
    const float reg = regime[b];

    // inline prior log-softmax (its barriers also publish the preloads)
    float px = prior_logits[s];
    {
        float wm0 = bflyMax(px);
        if (lane == 0) wrm[wv] = wm0;
    }
    lds_barrier();
    float pm = wrm[0];
#pragma unroll
    for (int i = 1; i < 8; ++i) pm = fmaxf(pm, wrm[i]);
    {
        float ws0 = bflySum(__expf(px - pm));
        if (lane == 0) wrs[wv] = ws0;
    }
    lds_barrier();
    float psum = wrs[0];
#pragma unroll
    for (int i = 1; i < 8; ++i) psum += wrs[i];
    float base_reg = px - pm - __logf(psum);   // prior_reg; loop-carried in reg

    // ---- prologue: issue step-0 chunks 0..7 into set F + obsv for t=0 ----
    ulonglong2 fA[8], fB[8], gA[8], gB[8];
    {
        const int a0 = __builtin_amdgcn_readfirstlane(act_l[0]);
        const unsigned char* P0 = PB + (size_t)a0 * (16 * 16384) + wvl16;
#pragma unroll
        for (int c = 0; c < 8; ++c) {
            fA[c] = *(const ulonglong2*)(P0 + c * 16384);
            fB[c] = *(const ulonglong2*)(P0 + c * 16384 + 1024);
        }
    }
    float obsv = obsT[(size_t)obs_l[0] * SS + s];

    float log_prob = 0.f;
    float was_done = 0.f;

// chunks 0..7: MFMA from CA/CB[c], refill CA/CB[c] with this step's chunk c+8
#define CHUNK_L(c, CA, CB)                                                      \
    {                                                                           \
        long af = *(const long long*)(p8 + quad * 144 + (c) * 8);               \
        acc0 = __builtin_amdgcn_mfma_f32_16x16x32_fp8_fp8((long)CA[(c)].x, af, acc0, 0, 0, 0); \
        acc1 = __builtin_amdgcn_mfma_f32_16x16x32_fp8_fp8((long)CA[(c)].y, af, acc1, 0, 0, 0); \
        acc2 = __builtin_amdgcn_mfma_f32_16x16x32_fp8_fp8((long)CB[(c)].x, af, acc2, 0, 0, 0); \
        acc3 = __builtin_amdgcn_mfma_f32_16x16x32_fp8_fp8((long)CB[(c)].y, af, acc3, 0, 0, 0); \
        CA[(c)] = *(const ulonglong2*)(Pw_ + ((c) + 8) * 16384);                \
        CB[(c)] = *(const ulonglong2*)(Pw_ + ((c) + 8) * 16384 + 1024);         \
    }
// chunks 8..15: MFMA from CA/CB[c-8], issue NEXT step's chunk c-8 into NA/NB
#define CHUNK_H(c, CA, CB, NA, NB)                                              \
    {                                                                           \
        long af = *(const long long*)(p8 + quad * 144 + (c) * 8);               \
        acc0 = __builtin_amdgcn_mfma_f32_16x16x32_fp8_fp8((long)CA[(c) - 8].x, af, acc0, 0, 0, 0); \
        acc1 = __builtin_amdgcn_mfma_f32_16x16x32_fp8_fp8((long)CA[(c) - 8].y, af, acc1, 0, 0, 0); \
        acc2 = __builtin_amdgcn_mfma_f32_16x16x32_fp8_fp8((long)CB[(c) - 8].x, af, acc2, 0, 0, 0); \
        acc3 = __builtin_amdgcn_mfma_f32_16x16x32_fp8_fp8((long)CB[(c) - 8].y, af, acc3, 0, 0, 0); \
        NA[(c) - 8] = *(const ulonglong2*)(Pn_ + ((c) - 8) * 16384);            \
        NB[(c) - 8] = *(const ulonglong2*)(Pn_ + ((c) - 8) * 16384 + 1024);     \
    }

#define STEP(T, CA, CB, NA, NB)                                                 \
    {                                                                           \
        const int t_ = (T);                                                     \
        const float r_ = rew_l[t_];                                             \
        const int a_ = __builtin_amdgcn_readfirstlane(act_l[t_]);               \
        const float d_ = done_l[t_];                                            \
        const float done_ = fmaxf(was_done, d_);                                \
        const unsigned char* Pw_ = PB + (size_t)a_ * (16 * 16384) + wvl16;      \
        const int tn_ = (t_ + 1 < TT) ? t_ + 1 : 0;                             \
        const int an_ = __builtin_amdgcn_readfirstlane(act_l[tn_]);             \
        const unsigned char* Pn_ = PB + (size_t)an_ * (16 * 16384) + wvl16;     \
        float obsv_next_ = obsT[(size_t)obs_l[t_ + 1] * SS + s];                \
        /* ---- phase A: emission + action term + block softmax ---- */        \
        float diff_ = (r_ - rm) * inv_sig;                                      \
        float emis_ = obsv - 0.5f * diff_ * diff_ - rls - 0.5f * LOG2PI;        \
        float la_ = la16[0];                                                    \
        _Pragma("unroll")                                                       \
        for (int i = 1; i < 16; ++i) la_ = (a_ == i) ? la16[i] : la_;           \
        if (done_ == 1.0f || reg == 1.0f) la_ = 0.f;                            \
        float lq_ = base_reg + emis_ + la_;                                     \
        float wmax_ = bflyMax(lq_);                                             \
        if (lane == 0) wrm[wv] = wmax_;                                         \
        lds_barrier(); /* B1 */                                                 \
        float m_ = wrm[0];                                                      \
        _Pragma("unroll")                                                       \
        for (int i = 1; i < 8; ++i) m_ = fmaxf(m_, wrm[i]);                     \
        float exv_ = __expf(lq_ - m_);                                          \
        p8[p8idx] = (unsigned char)f32_to_e4m3(exv_ * 16.0f);                   \
        float wsum_ = bflySum(exv_);                                            \
        if (lane == 0) wrs[wv] = wsum_;                                         \
        lds_barrier(); /* B2 (publishes p8) */                                  \
        float sum_ = wrs[0];                                                    \
        _Pragma("unroll")                                                       \
        for (int i = 1; i < 8; ++i) sum_ += wrs[i];                             \
        float lse_ = m_ + __logf(sum_);                                         \
        float lqo_ = lse_ * (1.0f - was_done);                                  \
        if (!isinf(log_prob)) log_prob += lqo_;                                 \
        was_done = done_;                                                       \
        /* ---- phase B: 16 ktiles; roll this step's 8..15 + next step's 0..7 */\
        const float basev_ = m_ - lqo_ - LOG4096;                               \
        f32x4 acc0 = {0.f, 0.f, 0.f, 0.f};                                      \
        f32x4 acc1 = {0.f, 0.f, 0.f, 0.f};                                      \
        f32x4 acc2 = {0.f, 0.f, 0.f, 0.f};                                      \
        f32x4 acc3 = {0.f, 0.f, 0.f, 0.f};                                      \
        CHUNK_L(0, CA, CB)  CHUNK_L(1, CA, CB)  CHUNK_L(2, CA, CB)              \
        CHUNK_L(3, CA, CB)  CHUNK_L(4, CA, CB)  CHUNK_L(5, CA, CB)              \
        CHUNK_L(6, CA, CB)  CHUNK_L(7, CA, CB)                                  \
        CHUNK_H(8, CA, CB, NA, NB)   CHUNK_H(9, CA, CB, NA, NB)                 \
        CHUNK_H(10, CA, CB, NA, NB)  CHUNK_H(11, CA, CB, NA, NB)                \
        CHUNK_H(12, CA, CB, NA, NB)  CHUNK_H(13, CA, CB, NA, NB)                \
        CHUNK_H(14, CA, CB, NA, NB)  CHUNK_H(15, CA, CB, NA, NB)                \
        /* ---- register-only handoff: state wv*64+16q+l = acc_q[0]@lane l */   \
        float t0_ = __shfl(acc0[0], lane & 15);                                 \
        float t1_ = __shfl(acc1[0], lane & 15);                                 \
        float t2_ = __shfl(acc2[0], lane & 15);                                 \
        float t3_ = __shfl(acc3[0], lane & 15);                                 \
        float av_ = quad == 0 ? t0_ : (quad == 1 ? t1_ : (quad == 2 ? t2_ : t3_)); \
        base_reg = basev_ + __logf(av_);                                        \
        obsv = obsv_next_;                                                      \
        asm volatile("" ::: "memory"); /* pin NXT loads inside this step */     \
    }

    for (int t = 0; t < TT; t += 2) {
        STEP(t, fA, fB, gA, gB)
        STEP(t + 1, gA, gB, fA, fB)
    }
#undef STEP
#undef CHUNK_L
#undef CHUNK_H

    // final step t = TT (no action term, no transition)
    {
        const float r = rew_l[TT];
        float diff = (r - rm) * inv_sig;
        float emis = obsv - 0.5f * diff * diff - rls - 0.5f * LOG2PI;
        float lq = base_reg + emis;
        float wmax = bflyMax(lq);
        if (lane == 0) wrm[wv] = wmax;
        lds_barrier();
        float m = wrm[0];
#pragma unroll
        for (int i = 1; i < 8; ++i) m = fmaxf(m, wrm[i]);
        float wsum = bflySum(__expf(lq - m));
        if (lane == 0) wrs[wv] = wsum;
        lds_barrier();
        float sum = wrs[0];
#pragma unroll
        for (int i = 1; i < 8; ++i) sum += wrs[i];
        float lse = m + __logf(sum);
        float lq_ord = lse * (1.0f - was_done);
        if (!isinf(log_prob)) log_prob += lq_ord;
    }

    if (tid == 0) out[b] = log_prob;
}

// ---------------- launch ----------------
extern "C" void kernel_launch(void* const* d_in, const int* in_sizes, int n_in,
                              void* d_out, int out_size, void* d_ws, size_t ws_size,
                              hipStream_t stream) {
    const float* regime = (const float*)d_in[0];
    const int* obs = (const int*)d_in[1];
    const float* rewards = (const float*)d_in[2];
    const float* dones = (const float*)d_in[3];
    const int* actions = (const int*)d_in[4];
    const float* prior_logits = (const float*)d_in[5];
    const float* trans_logits = (const float*)d_in[6];
    const float* obs_logits = (const float*)d_in[7];
    const float* policy_logits = (const float*)d_in[8];
    const float* r_mu = (const float*)d_in[9];
    const float* r_logsig = (const float*)d_in[10];
    float* out = (float*)d_out;

    char* ws = (char*)d_ws;
    unsigned char* PB = (unsigned char*)ws;                    // A*S*S fp8 = 4 MB
    float* obsT = (float*)(ws + (size_t)AA * SS * SS);         // O*S fp32 = 8 MB
    float* mo = (float*)(ws + (size_t)AA * SS * SS + (size_t)OO * SS * 4);  // S
    float* lo = mo + SS;                                       // S

    k_pre<<<384, 1024, 0, stream>>>(trans_logits, PB, obs_logits, mo, lo);
    k_obsT<<<(OO / 64) * (SS / 64), 256, 0, stream>>>(obs_logits, mo, lo, obsT);
    k_main<<<BB, 512, 0, stream>>>(regime, obs, rewards, dones, actions, prior_logits,
                                   PB, obsT, policy_logits, r_mu, r_logsig, out);
}